// Round 19
// baseline (118.707 us; speedup 1.0000x reference)
//
#include <hip/hip_runtime.h>
#include <hip/hip_bf16.h>
#include <math.h>

// Problem constants: B=2, T=2048, C=1024, H=16, Dh=64
#define GB 2
#define GT_SEQ 2048
#define GC 1024
#define GH 16
#define GDH 64
#define GM (GB * GT_SEQ)      // 4096 rows

typedef __attribute__((ext_vector_type(8))) short bf16x8;   // 8 bf16 = 4 VGPRs
typedef __attribute__((ext_vector_type(8))) unsigned short u16x8;
typedef __attribute__((ext_vector_type(4))) float f32x4;
typedef unsigned int u32;

#define QSCALE 0.18033688f   // 0.125 * log2(e): QK^T lands in log2 domain

__device__ __forceinline__ unsigned short f2bf(float f) {   // RNE f32 -> bf16
    unsigned int u = __float_as_uint(f);
    u += 0x7FFFu + ((u >> 16) & 1u);
    return (unsigned short)(u >> 16);
}
__device__ __forceinline__ float bf2f(unsigned short u) {   // exact bf16 -> f32
    return __uint_as_float(((unsigned int)u) << 16);
}
__device__ __forceinline__ float hw_exp2(float x) {         // v_exp_f32
    return __builtin_amdgcn_exp2f(x);
}
// pack 2 f32 -> u32 of 2 bf16 (lo in low half); compiler emits v_cvt_pk_bf16_f32
__device__ __forceinline__ u32 pk_bf16(float lo, float hi) {
    __hip_bfloat162 h = __float22bfloat162_rn(make_float2(lo, hi));
    return *reinterpret_cast<u32*>(&h);
}

// async global->LDS, 16B per lane; LDS dest is wave-uniform base (+lane*16 by HW)
#define GLOAD_LDS16(g, l) __builtin_amdgcn_global_load_lds( \
    (const __attribute__((address_space(1))) void*)(g),      \
    (__attribute__((address_space(3))) void*)(l), 16, 0, 0)

// swizzled fragment read: rows of 64 bf16 (128B = 8 chunks), chunk ^= (row&7)
__device__ __forceinline__ bf16x8 frag_ld(const char* base, int r, int kch) {
    return *reinterpret_cast<const bf16x8*>(base + r * 128 + ((kch ^ (r & 7)) << 4));
}

// ---------------- fused cast f32 -> bf16 (x | w_attn | w_proj, one launch) ----------------
__global__ __launch_bounds__(256) void cast3_f32_bf16(
    const float* __restrict__ a, unsigned short* __restrict__ oa, int na,
    const float* __restrict__ b, unsigned short* __restrict__ ob, int nb,
    const float* __restrict__ c, unsigned short* __restrict__ oc)
{
    const int i = (blockIdx.x * 256 + threadIdx.x) * 4;
    const float* src; unsigned short* dst; int off;
    if (i < na)            { src = a; dst = oa; off = i; }
    else if (i < na + nb)  { src = b; dst = ob; off = i - na; }
    else                   { src = c; dst = oc; off = i - na - nb; }
    const float4 v = *reinterpret_cast<const float4*>(&src[off]);
    ushort4 o;
    o.x = f2bf(v.x); o.y = f2bf(v.y); o.z = f2bf(v.z); o.w = f2bf(v.w);
    *reinterpret_cast<ushort4*>(&dst[off]) = o;
}

// ---------------- bf16 MFMA GEMM: C = A @ B^T + bias, f32 out (GEMM2) ----------------
__global__ __launch_bounds__(256) void gemm_mfma_bt(
    const unsigned short* __restrict__ A,   // [M][K] bf16
    const unsigned short* __restrict__ B,   // [N][K] bf16
    const float* __restrict__ bias,         // [N] f32
    float* __restrict__ Cf,                 // f32 out
    int M, int N, int K)
{
    __shared__ char As[128 * 128];
    __shared__ char Bs[128 * 128];

    const int tid  = threadIdx.x;
    const int lane = tid & 63;
    const int w    = tid >> 6;
    const int wm   = w >> 1;
    const int wn   = w & 1;

    // XCD swizzle (nwg % 8 == 0)
    const int gx  = gridDim.x;
    const int lid = blockIdx.y * gx + blockIdx.x;
    const int nwg = gx * gridDim.y;
    const int cpx = nwg >> 3;
    const int swz = (lid & 7) * cpx + (lid >> 3);
    const int m0 = (swz / gx) * 128;
    const int n0 = (swz % gx) * 128;

    f32x4 acc[4][4];
#pragma unroll
    for (int i = 0; i < 4; ++i)
#pragma unroll
        for (int j = 0; j < 4; ++j) acc[i][j] = (f32x4){0.f, 0.f, 0.f, 0.f};

    const int wbase = (tid & ~63);

    for (int k0 = 0; k0 < K; k0 += 64) {
        const char* Ag = (const char*)(A + (size_t)m0 * K + k0);
        const char* Bg = (const char*)(B + (size_t)n0 * K + k0);
#pragma unroll
        for (int i = 0; i < 4; ++i) {
            const int c = i * 256 + tid;
            const int row = c >> 3, cin = c & 7;
            const size_t goff = (size_t)row * (K * 2) + (size_t)((cin ^ (row & 7)) << 4);
            GLOAD_LDS16(Ag + goff, As + (i * 256 + wbase) * 16);
            GLOAD_LDS16(Bg + goff, Bs + (i * 256 + wbase) * 16);
        }
        __syncthreads();

#pragma unroll
        for (int ks = 0; ks < 2; ++ks) {
            const int kch = ks * 4 + (lane >> 4);
            bf16x8 a[4], b[4];
#pragma unroll
            for (int mi = 0; mi < 4; ++mi)
                a[mi] = frag_ld(As, wm * 64 + mi * 16 + (lane & 15), kch);
#pragma unroll
            for (int ni = 0; ni < 4; ++ni)
                b[ni] = frag_ld(Bs, wn * 64 + ni * 16 + (lane & 15), kch);
#pragma unroll
            for (int mi = 0; mi < 4; ++mi)
#pragma unroll
                for (int ni = 0; ni < 4; ++ni)
                    acc[mi][ni] = __builtin_amdgcn_mfma_f32_16x16x32_bf16(
                        a[mi], b[ni], acc[mi][ni], 0, 0, 0);
        }
        __syncthreads();
    }

    const int lc  = lane & 15;
    const int lr4 = (lane >> 4) * 4;
#pragma unroll
    for (int ni = 0; ni < 4; ++ni) {
        const int gcol = n0 + wn * 64 + ni * 16 + lc;
        const float bv = bias[gcol];
#pragma unroll
        for (int mi = 0; mi < 4; ++mi) {
            const int grow0 = m0 + wm * 64 + mi * 16 + lr4;
#pragma unroll
            for (int j = 0; j < 4; ++j)
                Cf[(size_t)(grow0 + j) * N + gcol] = acc[mi][ni][j] + bv;
        }
    }
}

// ---------------- GEMM1 fused: qkv projection; q scaled, k plain, V -> Vt (perm) ----------------
// Block-uniform epilogue select (1024 % 128 == 0): q cols -> qkvb*QSCALE,
// k cols -> qkvb, v cols -> Vt[bh][d][tile*64 + p] with the PV slot perm
// p = 32*(mi>>1) + 8*(lane>>4) + 4*(mi&1) + j (vectorized ushort4 over j).
__global__ __launch_bounds__(256) void gemm_qkv_vt(
    const unsigned short* __restrict__ A,    // [4096][1024] bf16 (x)
    const unsigned short* __restrict__ B,    // [3072][1024] bf16 (w_attn)
    const float* __restrict__ bias,          // [3072]
    unsigned short* __restrict__ qkvb,       // [4096][3072] (q,k thirds used)
    unsigned short* __restrict__ Vt)         // [32][64][2048] perm slots
{
    __shared__ char As[128 * 128];
    __shared__ char Bs[128 * 128];

    const int N = 3 * GC, K = GC;
    const int tid  = threadIdx.x;
    const int lane = tid & 63;
    const int w    = tid >> 6;
    const int wm   = w >> 1;
    const int wn   = w & 1;

    const int gx  = gridDim.x;                // 24
    const int lid = blockIdx.y * gx + blockIdx.x;
    const int nwg = gx * gridDim.y;           // 768
    const int cpx = nwg >> 3;
    const int swz = (lid & 7) * cpx + (lid >> 3);
    const int m0 = (swz / gx) * 128;
    const int n0 = (swz % gx) * 128;

    f32x4 acc[4][4];
#pragma unroll
    for (int i = 0; i < 4; ++i)
#pragma unroll
        for (int j = 0; j < 4; ++j) acc[i][j] = (f32x4){0.f, 0.f, 0.f, 0.f};

    const int wbase = (tid & ~63);

    for (int k0 = 0; k0 < K; k0 += 64) {
        const char* Ag = (const char*)(A + (size_t)m0 * K + k0);
        const char* Bg = (const char*)(B + (size_t)n0 * K + k0);
#pragma unroll
        for (int i = 0; i < 4; ++i) {
            const int c = i * 256 + tid;
            const int row = c >> 3, cin = c & 7;
            const size_t goff = (size_t)row * (K * 2) + (size_t)((cin ^ (row & 7)) << 4);
            GLOAD_LDS16(Ag + goff, As + (i * 256 + wbase) * 16);
            GLOAD_LDS16(Bg + goff, Bs + (i * 256 + wbase) * 16);
        }
        __syncthreads();

#pragma unroll
        for (int ks = 0; ks < 2; ++ks) {
            const int kch = ks * 4 + (lane >> 4);
            bf16x8 a[4], b[4];
#pragma unroll
            for (int mi = 0; mi < 4; ++mi)
                a[mi] = frag_ld(As, wm * 64 + mi * 16 + (lane & 15), kch);
#pragma unroll
            for (int ni = 0; ni < 4; ++ni)
                b[ni] = frag_ld(Bs, wn * 64 + ni * 16 + (lane & 15), kch);
#pragma unroll
            for (int mi = 0; mi < 4; ++mi)
#pragma unroll
                for (int ni = 0; ni < 4; ++ni)
                    acc[mi][ni] = __builtin_amdgcn_mfma_f32_16x16x32_bf16(
                        a[mi], b[ni], acc[mi][ni], 0, 0, 0);
        }
        __syncthreads();
    }

    const int lc  = lane & 15;
    const int lr4 = (lane >> 4) * 4;
    const int sel = n0 >> 10;                 // block-uniform: 0=q 1=k 2=v

    if (sel < 2) {
        const float scl = (sel == 0) ? QSCALE : 1.f;
#pragma unroll
        for (int ni = 0; ni < 4; ++ni) {
            const int gcol = n0 + wn * 64 + ni * 16 + lc;
            const float bv = bias[gcol];
#pragma unroll
            for (int mi = 0; mi < 4; ++mi) {
                const int grow0 = m0 + wm * 64 + mi * 16 + lr4;
#pragma unroll
                for (int j = 0; j < 4; ++j)
                    qkvb[(size_t)(grow0 + j) * N + gcol] =
                        f2bf((acc[mi][ni][j] + bv) * scl);
            }
        }
    } else {
        // V: write to Vt[bh][d][tile*64 + p], ushort4 over j
        const int h = ((n0 - 2048) >> 6) + wn;        // head for this wave-col
        const int b2 = lane >> 4;                     // = lr4/4
#pragma unroll
        for (int ni = 0; ni < 4; ++ni) {
            const int gcol = n0 + wn * 64 + ni * 16 + lc;
            const float bv = bias[gcol];
            const int d = ni * 16 + lc;
#pragma unroll
            for (int mi = 0; mi < 4; ++mi) {
                const int grow0 = m0 + wm * 64 + mi * 16 + lr4;  // j=0 row
                const int bb   = grow0 >> 11;                     // batch
                const int tile = (grow0 & 2047) >> 6;
                const int p0   = 32 * (mi >> 1) + 8 * b2 + 4 * (mi & 1);
                const int bh   = bb * GH + h;
                ushort4 o;
                o.x = f2bf(acc[mi][ni][0] + bv);
                o.y = f2bf(acc[mi][ni][1] + bv);
                o.z = f2bf(acc[mi][ni][2] + bv);
                o.w = f2bf(acc[mi][ni][3] + bv);
                *reinterpret_cast<ushort4*>(
                    Vt + ((size_t)bh * GDH + d) * GT_SEQ + tile * 64 + p0) = o;
            }
        }
    }
}

// ---------------- flash attention v9d: r18 core, Q pre-scaled upstream ----------------
__global__ __launch_bounds__(256) void flash_attn_mfma9(
    const unsigned short* __restrict__ qkvb,  // [4096][3072] bf16: q(scaled)|k|v-unused
    const unsigned short* __restrict__ Vt,    // [32][64][2048] (perm slots)
    unsigned short* __restrict__ O)           // [4096][1024] bf16
{
    __shared__ __align__(16) char Ks[2][64 * 128];   // K tile: row k, 64 d bf16, swizzled
    __shared__ __align__(16) char Vs[2][64 * 128];   // V^T tile: row d, 64 slots, swizzled

    const int tid  = threadIdx.x;
    const int lane = tid & 63;
    const int w    = tid >> 6;               // wave 0..3
    const int l15  = lane & 15;
    const int l4   = lane >> 4;
    const int bid  = blockIdx.x;              // 0..1023
    const int xcd  = bid & 7;
    const int rest = bid >> 3;                // 0..127
    const int bh   = xcd * 4 + (rest & 3);    // 0..31
    const int qb   = 31 - (rest >> 2);        // 0..31 (64-row blocks), heavy first
    const int b    = bh >> 4, h = bh & 15;
    const int q0w  = qb * 64 + w * 16;        // this wave's 16 q rows

    const unsigned short* hQ = qkvb + (size_t)(b * GT_SEQ) * (3 * GC) + h * GDH;
    const char* hKc = (const char*)(qkvb + (size_t)(b * GT_SEQ) * (3 * GC) + GC + h * GDH);
    const char* hVc = (const char*)(Vt + (size_t)bh * GDH * GT_SEQ);

    // all-ones A-fragment: acc_l = mfma(ones, P) -> l_q in every reg
    bf16x8 ones_a;
#pragma unroll
    for (int e = 0; e < 8; ++e) ones_a[e] = (short)0x3F80;

    // Q fragments (pre-scaled by GEMM1): qf[s], q row = l15, d = s*32+l4*8+e
    bf16x8 qf[2];
#pragma unroll
    for (int s = 0; s < 2; ++s)
        qf[s] = *reinterpret_cast<const bf16x8*>(
            hQ + (size_t)(q0w + l15) * (3 * GC) + s * 32 + l4 * 8);

    f32x4 acc_o[4];
    f32x4 acc_l = (f32x4){0.f, 0.f, 0.f, 0.f};
    float m_r = -1e30f;
#pragma unroll
    for (int nd = 0; nd < 4; ++nd) acc_o[nd] = (f32x4){0.f, 0.f, 0.f, 0.f};

    const int nt = qb + 1;
    const int wbase16 = (tid & ~63) * 16;

    // stage tile t into buffer bb: source pre-swizzled, dest linear (rule 21)
    auto STAGE = [&](int bb, int t) {
        const int k0 = t * 64;
#pragma unroll
        for (int i = 0; i < 2; ++i) {
            const int c = i * 256 + tid;
            const int row = c >> 3, cin = c & 7;
            GLOAD_LDS16(hKc + (size_t)(k0 + row) * (3 * GC * 2) + ((cin ^ (row & 7)) << 4),
                        Ks[bb] + i * 4096 + wbase16);
            GLOAD_LDS16(hVc + (size_t)row * 4096 + (size_t)k0 * 2 + ((cin ^ (row & 7)) << 4),
                        Vs[bb] + i * 4096 + wbase16);
        }
    };

    STAGE(0, 0);
    __syncthreads();

    for (int t = 0; t < nt; ++t) {
        if (t + 1 < nt) STAGE((t + 1) & 1, t + 1);

        const int k0 = t * 64;
        const char* Kb = Ks[t & 1];
        const char* Vb = Vs[t & 1];

        if (k0 <= q0w + 15) {   // wave-uniform skip of fully-masked tiles
            // ---- QK^T swapped: S^T = mfma(K, Q), K fragments from LDS ----
            f32x4 s_acc[4];
#pragma unroll
            for (int ni = 0; ni < 4; ++ni) s_acc[ni] = (f32x4){0.f, 0.f, 0.f, 0.f};
#pragma unroll
            for (int s = 0; s < 2; ++s) {
                bf16x8 kf[4];
#pragma unroll
                for (int ni = 0; ni < 4; ++ni)
                    kf[ni] = frag_ld(Kb, ni * 16 + l15, s * 4 + l4);
#pragma unroll
                for (int ni = 0; ni < 4; ++ni)
                    s_acc[ni] = __builtin_amdgcn_mfma_f32_16x16x32_bf16(
                        kf[ni], qf[s], s_acc[ni], 0, 0, 0);
            }

            // ---- causal mask (partial tiles only): k > q -> -inf ----
            if (k0 + 63 > q0w) {
#pragma unroll
                for (int ni = 0; ni < 4; ++ni)
#pragma unroll
                    for (int j = 0; j < 4; ++j)
                        if (k0 + ni * 16 + l4 * 4 + j > q0w + l15)
                            s_acc[ni][j] = -1e30f;
            }

            // ---- deferred-max: in-lane partial max, rare rescale ----
            float r = fmaxf(fmaxf(s_acc[0][0], s_acc[0][1]),
                            fmaxf(s_acc[0][2], s_acc[0][3]));
#pragma unroll
            for (int ni = 1; ni < 4; ++ni)
                r = fmaxf(r, fmaxf(fmaxf(s_acc[ni][0], s_acc[ni][1]),
                                   fmaxf(s_acc[ni][2], s_acc[ni][3])));
            const int ok = (r <= m_r + 8.f) ? 1 : 0;
            if (!__all(ok)) {
                r = fmaxf(r, __shfl_xor(r, 16));
                r = fmaxf(r, __shfl_xor(r, 32));
                const float mnew = fmaxf(m_r, r);
                const float corr = hw_exp2(m_r - mnew);
                m_r = mnew;
                acc_l *= corr;
#pragma unroll
                for (int nd = 0; nd < 4; ++nd) acc_o[nd] *= corr;
            }

            // ---- exp2 + cvt_pk + PV per s; l via ones-MFMA; V via frag_ld ----
#pragma unroll
            for (int s = 0; s < 2; ++s) {
                union { u32 w4[4]; bf16x8 v; } pw;
                {
                    f32x4 pa, pb;
#pragma unroll
                    for (int j = 0; j < 4; ++j) {
                        pa[j] = hw_exp2(s_acc[2 * s + 0][j] - m_r);
                        pb[j] = hw_exp2(s_acc[2 * s + 1][j] - m_r);
                    }
                    pw.w4[0] = pk_bf16(pa[0], pa[1]);
                    pw.w4[1] = pk_bf16(pa[2], pa[3]);
                    pw.w4[2] = pk_bf16(pb[0], pb[1]);
                    pw.w4[3] = pk_bf16(pb[2], pb[3]);
                }
                acc_l = __builtin_amdgcn_mfma_f32_16x16x32_bf16(
                    ones_a, pw.v, acc_l, 0, 0, 0);
#pragma unroll
                for (int nd = 0; nd < 4; ++nd) {
                    const bf16x8 vf = frag_ld(Vb, nd * 16 + l15, s * 4 + l4);
                    acc_o[nd] = __builtin_amdgcn_mfma_f32_16x16x32_bf16(
                        vf, pw.v, acc_o[nd], 0, 0, 0);
                }
            }
        }

        __syncthreads();
    }

    // ---- epilogue: l = acc_l[0] (same in all regs), normalize, store ----
    {
        const float inv = 1.f / acc_l[0];
        const int q = q0w + l15;
        const size_t rbase = (size_t)(b * GT_SEQ + q) * GC + h * GDH;
#pragma unroll
        for (int nd = 0; nd < 4; ++nd) {
            ushort4 ov;
            ov.x = f2bf(acc_o[nd][0] * inv);
            ov.y = f2bf(acc_o[nd][1] * inv);
            ov.z = f2bf(acc_o[nd][2] * inv);
            ov.w = f2bf(acc_o[nd][3] * inv);
            *reinterpret_cast<ushort4*>(&O[rbase + nd * 16 + l4 * 4]) = ov;
        }
    }
}

extern "C" void kernel_launch(void* const* d_in, const int* in_sizes, int n_in,
                              void* d_out, int out_size, void* d_ws, size_t ws_size,
                              hipStream_t stream) {
    (void)in_sizes; (void)n_in; (void)out_size; (void)ws_size;
    const float* x      = (const float*)d_in[0];
    const float* w_attn = (const float*)d_in[1];
    const float* b_attn = (const float*)d_in[2];
    const float* w_proj = (const float*)d_in[3];
    const float* b_proj = (const float*)d_in[4];
    float* out = (float*)d_out;

    unsigned short* xb   = (unsigned short*)d_ws;            // [4096][1024]
    unsigned short* wab  = xb   + (size_t)GM * GC;           // [3072][1024]
    unsigned short* wpb  = wab  + (size_t)3 * GC * GC;       // [1024][1024]
    unsigned short* qkvb = wpb  + (size_t)GC * GC;           // [4096][3072]
    unsigned short* Vt   = qkvb + (size_t)GM * 3 * GC;       // [32][64][2048]
    unsigned short* aob  = xb;   // reuse: xb dead after GEMM1

    // 0) fused casts: x(4M) | w_attn(3M) | w_proj(1M) = 8M elems
    cast3_f32_bf16<<<dim3(8192), dim3(256), 0, stream>>>(
        x, xb, GM * GC, w_attn, wab, 3 * GC * GC, w_proj, wpb);

    // 1) qkv projection fused with V-transpose-perm; q pre-scaled. grid 24x32=768
    gemm_qkv_vt<<<dim3(3 * GC / 128, GM / 128), dim3(256), 0, stream>>>(
        xb, wab, b_attn, qkvb, Vt);

    // 2) flash attention v9d -> aob
    flash_attn_mfma9<<<dim3(1024), dim3(256), 0, stream>>>(qkvb, Vt, aob);

    // 3) out = aob @ w_proj^T + b_proj (f32), grid 8x32 = 256 (%8==0)
    gemm_mfma_bt<<<dim3(GC / 128, GM / 128), dim3(256), 0, stream>>>(
        aob, wpb, b_proj, out, GM, GC, GC);
}

// Round 20
// 115.766 us; speedup vs baseline: 1.0254x; 1.0254x over previous
//
#include <hip/hip_runtime.h>
#include <hip/hip_bf16.h>
#include <math.h>

// Problem constants: B=2, T=2048, C=1024, H=16, Dh=64
#define GB 2
#define GT_SEQ 2048
#define GC 1024
#define GH 16
#define GDH 64
#define GM (GB * GT_SEQ)      // 4096 rows

typedef __attribute__((ext_vector_type(8))) short bf16x8;   // 8 bf16 = 4 VGPRs
typedef __attribute__((ext_vector_type(8))) unsigned short u16x8;
typedef __attribute__((ext_vector_type(4))) float f32x4;
typedef unsigned int u32;

#define QSCALE 0.18033688f   // 0.125 * log2(e): QK^T lands in log2 domain

__device__ __forceinline__ unsigned short f2bf(float f) {   // RNE f32 -> bf16
    unsigned int u = __float_as_uint(f);
    u += 0x7FFFu + ((u >> 16) & 1u);
    return (unsigned short)(u >> 16);
}
__device__ __forceinline__ float bf2f(unsigned short u) {   // exact bf16 -> f32
    return __uint_as_float(((unsigned int)u) << 16);
}
__device__ __forceinline__ float hw_exp2(float x) {         // v_exp_f32
    return __builtin_amdgcn_exp2f(x);
}
// pack 2 f32 -> u32 of 2 bf16 (lo in low half); compiler emits v_cvt_pk_bf16_f32
__device__ __forceinline__ u32 pk_bf16(float lo, float hi) {
    __hip_bfloat162 h = __float22bfloat162_rn(make_float2(lo, hi));
    return *reinterpret_cast<u32*>(&h);
}

// async global->LDS, 16B per lane; LDS dest is wave-uniform base (+lane*16 by HW)
#define GLOAD_LDS16(g, l) __builtin_amdgcn_global_load_lds( \
    (const __attribute__((address_space(1))) void*)(g),      \
    (__attribute__((address_space(3))) void*)(l), 16, 0, 0)

// swizzled fragment read: rows of 64 bf16 (128B = 8 chunks), chunk ^= (row&7)
__device__ __forceinline__ bf16x8 frag_ld(const char* base, int r, int kch) {
    return *reinterpret_cast<const bf16x8*>(base + r * 128 + ((kch ^ (r & 7)) << 4));
}

// ---------------- fused cast f32 -> bf16 (x | w_attn | w_proj, one launch) ----------------
__global__ __launch_bounds__(256) void cast3_f32_bf16(
    const float* __restrict__ a, unsigned short* __restrict__ oa, int na,
    const float* __restrict__ b, unsigned short* __restrict__ ob, int nb,
    const float* __restrict__ c, unsigned short* __restrict__ oc)
{
    const int i = (blockIdx.x * 256 + threadIdx.x) * 4;
    const float* src; unsigned short* dst; int off;
    if (i < na)            { src = a; dst = oa; off = i; }
    else if (i < na + nb)  { src = b; dst = ob; off = i - na; }
    else                   { src = c; dst = oc; off = i - na - nb; }
    const float4 v = *reinterpret_cast<const float4*>(&src[off]);
    ushort4 o;
    o.x = f2bf(v.x); o.y = f2bf(v.y); o.z = f2bf(v.z); o.w = f2bf(v.w);
    *reinterpret_cast<ushort4*>(&dst[off]) = o;
}

// ---------------- bf16 MFMA GEMM: C = A @ B^T + bias (validated rounds 2-18) ----------------
// Cb path: bf16 out, with QSCALE applied to cols < 1024 (q third; GEMM1 only).
// Cf path: f32 out (GEMM2).  XCD-swizzled lid (nwg % 8 == 0).
__global__ __launch_bounds__(256) void gemm_mfma_bt(
    const unsigned short* __restrict__ A,   // [M][K] bf16
    const unsigned short* __restrict__ B,   // [N][K] bf16
    const float* __restrict__ bias,         // [N] f32
    float* __restrict__ Cf,                 // f32 out (or null)
    unsigned short* __restrict__ Cb,        // bf16 out (or null)
    int M, int N, int K)
{
    __shared__ char As[128 * 128];
    __shared__ char Bs[128 * 128];

    const int tid  = threadIdx.x;
    const int lane = tid & 63;
    const int w    = tid >> 6;
    const int wm   = w >> 1;
    const int wn   = w & 1;

    const int gx  = gridDim.x;
    const int lid = blockIdx.y * gx + blockIdx.x;
    const int nwg = gx * gridDim.y;
    const int cpx = nwg >> 3;                 // nwg % 8 == 0 (768, 256)
    const int swz = (lid & 7) * cpx + (lid >> 3);
    const int m0 = (swz / gx) * 128;
    const int n0 = (swz % gx) * 128;

    f32x4 acc[4][4];
#pragma unroll
    for (int i = 0; i < 4; ++i)
#pragma unroll
        for (int j = 0; j < 4; ++j) acc[i][j] = (f32x4){0.f, 0.f, 0.f, 0.f};

    const int wbase = (tid & ~63);

    for (int k0 = 0; k0 < K; k0 += 64) {
        const char* Ag = (const char*)(A + (size_t)m0 * K + k0);
        const char* Bg = (const char*)(B + (size_t)n0 * K + k0);
#pragma unroll
        for (int i = 0; i < 4; ++i) {
            const int c = i * 256 + tid;
            const int row = c >> 3, cin = c & 7;
            const size_t goff = (size_t)row * (K * 2) + (size_t)((cin ^ (row & 7)) << 4);
            GLOAD_LDS16(Ag + goff, As + (i * 256 + wbase) * 16);
            GLOAD_LDS16(Bg + goff, Bs + (i * 256 + wbase) * 16);
        }
        __syncthreads();

#pragma unroll
        for (int ks = 0; ks < 2; ++ks) {
            const int kch = ks * 4 + (lane >> 4);
            bf16x8 a[4], b[4];
#pragma unroll
            for (int mi = 0; mi < 4; ++mi)
                a[mi] = frag_ld(As, wm * 64 + mi * 16 + (lane & 15), kch);
#pragma unroll
            for (int ni = 0; ni < 4; ++ni)
                b[ni] = frag_ld(Bs, wn * 64 + ni * 16 + (lane & 15), kch);
#pragma unroll
            for (int mi = 0; mi < 4; ++mi)
#pragma unroll
                for (int ni = 0; ni < 4; ++ni)
                    acc[mi][ni] = __builtin_amdgcn_mfma_f32_16x16x32_bf16(
                        a[mi], b[ni], acc[mi][ni], 0, 0, 0);
        }
        __syncthreads();
    }

    const int lc  = lane & 15;
    const int lr4 = (lane >> 4) * 4;
#pragma unroll
    for (int ni = 0; ni < 4; ++ni) {
        const int gcol = n0 + wn * 64 + ni * 16 + lc;
        const float bv = bias[gcol];
        const float scl = (Cb && gcol < GC) ? QSCALE : 1.f;   // q third pre-scale
#pragma unroll
        for (int mi = 0; mi < 4; ++mi) {
            const int grow0 = m0 + wm * 64 + mi * 16 + lr4;
#pragma unroll
            for (int j = 0; j < 4; ++j) {
                const float v = (acc[mi][ni][j] + bv) * scl;
                if (Cb) Cb[(size_t)(grow0 + j) * N + gcol] = f2bf(v);
                else    Cf[(size_t)(grow0 + j) * N + gcol] = v;
            }
        }
    }
}

// ---------------- V transpose + PV-slot permutation (validated r18) ----------------
// Vt[bh][d][32 tiles x 64 perm-slots]: position p = 32s + 8*l4 + e holds
// V[t = 32s + 16*(e>>2) + 4*l4 + (e&3)][d] — matches the P B-fragment slot map.
__global__ __launch_bounds__(256) void transpose_v(
    const unsigned short* __restrict__ qkvb, unsigned short* __restrict__ Vt)
{
    __shared__ unsigned short vt[64][72];
    const int tid = threadIdx.x;
    const int t0  = blockIdx.x * 64;
    const int bh  = blockIdx.y;
    const int b = bh >> 4, h = bh & 15;
    const unsigned short* src = qkvb + (size_t)(b * GT_SEQ) * (3 * GC) + 2 * GC + h * GDH;
    unsigned short* dstb = Vt + (size_t)bh * GDH * GT_SEQ;

#pragma unroll
    for (int i = 0; i < 2; ++i) {
        const int c = i * 256 + tid;
        const int tr = c >> 3, ch = c & 7;
        *reinterpret_cast<u16x8*>(&vt[tr][ch * 8]) =
            *reinterpret_cast<const u16x8*>(src + (size_t)(t0 + tr) * (3 * GC) + ch * 8);
    }
    __syncthreads();
#pragma unroll
    for (int i = 0; i < 2; ++i) {
        const int c = i * 256 + tid;
        const int d = c >> 3, ch = c & 7;
        const int s = ch >> 2, l4p = ch & 3;
        u16x8 o;
#pragma unroll
        for (int e = 0; e < 8; ++e) {
            const int tp = s * 32 + (e >> 2) * 16 + l4p * 4 + (e & 3);
            o[e] = vt[tp][d];
        }
        *reinterpret_cast<u16x8*>(dstb + (size_t)d * GT_SEQ + t0 + ch * 8) = o;
    }
}

// ---------------- flash attention v9e: r18 core + pre-scaled Q + setprio (T5) ----------------
__global__ __launch_bounds__(256) void flash_attn_mfma9(
    const unsigned short* __restrict__ qkvb,  // [4096][3072] bf16: q(scaled)|k|v
    const unsigned short* __restrict__ Vt,    // [32][64][2048] (perm slots)
    unsigned short* __restrict__ O)           // [4096][1024] bf16
{
    __shared__ __align__(16) char Ks[2][64 * 128];   // K tile: row k, 64 d bf16, swizzled
    __shared__ __align__(16) char Vs[2][64 * 128];   // V^T tile: row d, 64 slots, swizzled

    const int tid  = threadIdx.x;
    const int lane = tid & 63;
    const int w    = tid >> 6;               // wave 0..3
    const int l15  = lane & 15;
    const int l4   = lane >> 4;
    const int bid  = blockIdx.x;              // 0..1023
    const int xcd  = bid & 7;
    const int rest = bid >> 3;                // 0..127
    const int bh   = xcd * 4 + (rest & 3);    // 0..31
    const int qb   = 31 - (rest >> 2);        // 0..31 (64-row blocks), heavy first
    const int b    = bh >> 4, h = bh & 15;
    const int q0w  = qb * 64 + w * 16;        // this wave's 16 q rows

    const unsigned short* hQ = qkvb + (size_t)(b * GT_SEQ) * (3 * GC) + h * GDH;
    const char* hKc = (const char*)(qkvb + (size_t)(b * GT_SEQ) * (3 * GC) + GC + h * GDH);
    const char* hVc = (const char*)(Vt + (size_t)bh * GDH * GT_SEQ);

    // all-ones A-fragment: acc_l = mfma(ones, P) -> l_q in every reg
    bf16x8 ones_a;
#pragma unroll
    for (int e = 0; e < 8; ++e) ones_a[e] = (short)0x3F80;

    // Q fragments (pre-scaled by GEMM1): qf[s], q row = l15, d = s*32+l4*8+e
    bf16x8 qf[2];
#pragma unroll
    for (int s = 0; s < 2; ++s)
        qf[s] = *reinterpret_cast<const bf16x8*>(
            hQ + (size_t)(q0w + l15) * (3 * GC) + s * 32 + l4 * 8);

    f32x4 acc_o[4];
    f32x4 acc_l = (f32x4){0.f, 0.f, 0.f, 0.f};
    float m_r = -1e30f;
#pragma unroll
    for (int nd = 0; nd < 4; ++nd) acc_o[nd] = (f32x4){0.f, 0.f, 0.f, 0.f};

    const int nt = qb + 1;
    const int wbase16 = (tid & ~63) * 16;

    // stage tile t into buffer bb: source pre-swizzled, dest linear (rule 21)
    auto STAGE = [&](int bb, int t) {
        const int k0 = t * 64;
#pragma unroll
        for (int i = 0; i < 2; ++i) {
            const int c = i * 256 + tid;
            const int row = c >> 3, cin = c & 7;
            GLOAD_LDS16(hKc + (size_t)(k0 + row) * (3 * GC * 2) + ((cin ^ (row & 7)) << 4),
                        Ks[bb] + i * 4096 + wbase16);
            GLOAD_LDS16(hVc + (size_t)row * 4096 + (size_t)k0 * 2 + ((cin ^ (row & 7)) << 4),
                        Vs[bb] + i * 4096 + wbase16);
        }
    };

    STAGE(0, 0);
    __syncthreads();

    for (int t = 0; t < nt; ++t) {
        if (t + 1 < nt) STAGE((t + 1) & 1, t + 1);

        const int k0 = t * 64;
        const char* Kb = Ks[t & 1];
        const char* Vb = Vs[t & 1];

        if (k0 <= q0w + 15) {   // wave-uniform skip of fully-masked tiles
            // ---- QK^T swapped: S^T = mfma(K, Q), K fragments from LDS ----
            f32x4 s_acc[4];
#pragma unroll
            for (int ni = 0; ni < 4; ++ni) s_acc[ni] = (f32x4){0.f, 0.f, 0.f, 0.f};
            __builtin_amdgcn_s_setprio(1);
#pragma unroll
            for (int s = 0; s < 2; ++s) {
                bf16x8 kf[4];
#pragma unroll
                for (int ni = 0; ni < 4; ++ni)
                    kf[ni] = frag_ld(Kb, ni * 16 + l15, s * 4 + l4);
#pragma unroll
                for (int ni = 0; ni < 4; ++ni)
                    s_acc[ni] = __builtin_amdgcn_mfma_f32_16x16x32_bf16(
                        kf[ni], qf[s], s_acc[ni], 0, 0, 0);
            }
            __builtin_amdgcn_s_setprio(0);

            // ---- causal mask (partial tiles only): k > q -> -inf ----
            if (k0 + 63 > q0w) {
#pragma unroll
                for (int ni = 0; ni < 4; ++ni)
#pragma unroll
                    for (int j = 0; j < 4; ++j)
                        if (k0 + ni * 16 + l4 * 4 + j > q0w + l15)
                            s_acc[ni][j] = -1e30f;
            }

            // ---- deferred-max: in-lane partial max, rare rescale ----
            float r = fmaxf(fmaxf(s_acc[0][0], s_acc[0][1]),
                            fmaxf(s_acc[0][2], s_acc[0][3]));
#pragma unroll
            for (int ni = 1; ni < 4; ++ni)
                r = fmaxf(r, fmaxf(fmaxf(s_acc[ni][0], s_acc[ni][1]),
                                   fmaxf(s_acc[ni][2], s_acc[ni][3])));
            const int ok = (r <= m_r + 8.f) ? 1 : 0;
            if (!__all(ok)) {
                r = fmaxf(r, __shfl_xor(r, 16));
                r = fmaxf(r, __shfl_xor(r, 32));
                const float mnew = fmaxf(m_r, r);
                const float corr = hw_exp2(m_r - mnew);
                m_r = mnew;
                acc_l *= corr;
#pragma unroll
                for (int nd = 0; nd < 4; ++nd) acc_o[nd] *= corr;
            }

            // ---- exp2 + cvt_pk + PV per s; l via ones-MFMA; V via frag_ld ----
            __builtin_amdgcn_s_setprio(1);
#pragma unroll
            for (int s = 0; s < 2; ++s) {
                union { u32 w4[4]; bf16x8 v; } pw;
                {
                    f32x4 pa, pb;
#pragma unroll
                    for (int j = 0; j < 4; ++j) {
                        pa[j] = hw_exp2(s_acc[2 * s + 0][j] - m_r);
                        pb[j] = hw_exp2(s_acc[2 * s + 1][j] - m_r);
                    }
                    pw.w4[0] = pk_bf16(pa[0], pa[1]);
                    pw.w4[1] = pk_bf16(pa[2], pa[3]);
                    pw.w4[2] = pk_bf16(pb[0], pb[1]);
                    pw.w4[3] = pk_bf16(pb[2], pb[3]);
                }
                acc_l = __builtin_amdgcn_mfma_f32_16x16x32_bf16(
                    ones_a, pw.v, acc_l, 0, 0, 0);
#pragma unroll
                for (int nd = 0; nd < 4; ++nd) {
                    const bf16x8 vf = frag_ld(Vb, nd * 16 + l15, s * 4 + l4);
                    acc_o[nd] = __builtin_amdgcn_mfma_f32_16x16x32_bf16(
                        vf, pw.v, acc_o[nd], 0, 0, 0);
                }
            }
            __builtin_amdgcn_s_setprio(0);
        }

        __syncthreads();
    }

    // ---- epilogue: l = acc_l[0] (same in all regs), normalize, store ----
    {
        const float inv = 1.f / acc_l[0];
        const int q = q0w + l15;
        const size_t rbase = (size_t)(b * GT_SEQ + q) * GC + h * GDH;
#pragma unroll
        for (int nd = 0; nd < 4; ++nd) {
            ushort4 ov;
            ov.x = f2bf(acc_o[nd][0] * inv);
            ov.y = f2bf(acc_o[nd][1] * inv);
            ov.z = f2bf(acc_o[nd][2] * inv);
            ov.w = f2bf(acc_o[nd][3] * inv);
            *reinterpret_cast<ushort4*>(&O[rbase + nd * 16 + l4 * 4]) = ov;
        }
    }
}

extern "C" void kernel_launch(void* const* d_in, const int* in_sizes, int n_in,
                              void* d_out, int out_size, void* d_ws, size_t ws_size,
                              hipStream_t stream) {
    (void)in_sizes; (void)n_in; (void)out_size; (void)ws_size;
    const float* x      = (const float*)d_in[0];
    const float* w_attn = (const float*)d_in[1];
    const float* b_attn = (const float*)d_in[2];
    const float* w_proj = (const float*)d_in[3];
    const float* b_proj = (const float*)d_in[4];
    float* out = (float*)d_out;

    unsigned short* xb   = (unsigned short*)d_ws;            // [4096][1024]
    unsigned short* wab  = xb   + (size_t)GM * GC;           // [3072][1024]
    unsigned short* wpb  = wab  + (size_t)3 * GC * GC;       // [1024][1024]
    unsigned short* qkvb = wpb  + (size_t)GC * GC;           // [4096][3072]
    unsigned short* Vt   = qkvb + (size_t)GM * 3 * GC;       // [32][64][2048]
    unsigned short* aob  = xb;   // reuse: xb dead after GEMM1

    // 0) fused casts: x(4M) | w_attn(3M) | w_proj(1M) = 8M elems
    cast3_f32_bf16<<<dim3(8192), dim3(256), 0, stream>>>(
        x, xb, GM * GC, w_attn, wab, 3 * GC * GC, w_proj, wpb);

    // 1) qkv = x @ w_attn^T + b_attn (bf16, q third pre-scaled). grid 24x32=768
    gemm_mfma_bt<<<dim3(3 * GC / 128, GM / 128), dim3(256), 0, stream>>>(
        xb, wab, b_attn, nullptr, qkvb, GM, 3 * GC, GC);

    // 1.5) V transpose (+ PV-slot permutation) from qkvb -> Vt
    transpose_v<<<dim3(GT_SEQ / 64, GB * GH), dim3(256), 0, stream>>>(qkvb, Vt);

    // 2) flash attention v9e -> aob
    flash_attn_mfma9<<<dim3(1024), dim3(256), 0, stream>>>(qkvb, Vt, aob);

    // 3) out = aob @ w_proj^T + b_proj (f32), grid 8x32 = 256 (%8==0)
    gemm_mfma_bt<<<dim3(GC / 128, GM / 128), dim3(256), 0, stream>>>(
        aob, wpb, b_proj, out, nullptr, GM, GC, GC);
}

// Round 21
// 113.353 us; speedup vs baseline: 1.0472x; 1.0213x over previous
//
#include <hip/hip_runtime.h>
#include <hip/hip_bf16.h>
#include <math.h>

// Problem constants: B=2, T=2048, C=1024, H=16, Dh=64
#define GB 2
#define GT_SEQ 2048
#define GC 1024
#define GH 16
#define GDH 64
#define GM (GB * GT_SEQ)      // 4096 rows

typedef __attribute__((ext_vector_type(8))) short bf16x8;   // 8 bf16 = 4 VGPRs
typedef __attribute__((ext_vector_type(8))) unsigned short u16x8;
typedef __attribute__((ext_vector_type(4))) float f32x4;
typedef unsigned int u32;

#define QSCALE 0.18033688f   // 0.125 * log2(e): QK^T lands in log2 domain

__device__ __forceinline__ unsigned short f2bf(float f) {   // RNE f32 -> bf16
    unsigned int u = __float_as_uint(f);
    u += 0x7FFFu + ((u >> 16) & 1u);
    return (unsigned short)(u >> 16);
}
__device__ __forceinline__ float bf2f(unsigned short u) {   // exact bf16 -> f32
    return __uint_as_float(((unsigned int)u) << 16);
}
__device__ __forceinline__ float hw_exp2(float x) {         // v_exp_f32
    return __builtin_amdgcn_exp2f(x);
}
// pack 2 f32 -> u32 of 2 bf16 (lo in low half); compiler emits v_cvt_pk_bf16_f32
__device__ __forceinline__ u32 pk_bf16(float lo, float hi) {
    __hip_bfloat162 h = __float22bfloat162_rn(make_float2(lo, hi));
    return *reinterpret_cast<u32*>(&h);
}

// async global->LDS, 16B per lane; LDS dest is wave-uniform base (+lane*16 by HW)
#define GLOAD_LDS16(g, l) __builtin_amdgcn_global_load_lds( \
    (const __attribute__((address_space(1))) void*)(g),      \
    (__attribute__((address_space(3))) void*)(l), 16, 0, 0)

// swizzled fragment read: rows of 64 bf16 (128B = 8 chunks), chunk ^= (row&7)
__device__ __forceinline__ bf16x8 frag_ld(const char* base, int r, int kch) {
    return *reinterpret_cast<const bf16x8*>(base + r * 128 + ((kch ^ (r & 7)) << 4));
}

// ---------------- fused cast f32 -> bf16 (x | w_attn | w_proj, one launch) ----------------
__global__ __launch_bounds__(256) void cast3_f32_bf16(
    const float* __restrict__ a, unsigned short* __restrict__ oa, int na,
    const float* __restrict__ b, unsigned short* __restrict__ ob, int nb,
    const float* __restrict__ c, unsigned short* __restrict__ oc)
{
    const int i = (blockIdx.x * 256 + threadIdx.x) * 4;
    const float* src; unsigned short* dst; int off;
    if (i < na)            { src = a; dst = oa; off = i; }
    else if (i < na + nb)  { src = b; dst = ob; off = i - na; }
    else                   { src = c; dst = oc; off = i - na - nb; }
    const float4 v = *reinterpret_cast<const float4*>(&src[off]);
    ushort4 o;
    o.x = f2bf(v.x); o.y = f2bf(v.y); o.z = f2bf(v.z); o.w = f2bf(v.w);
    *reinterpret_cast<ushort4*>(&dst[off]) = o;
}

// ---------------- bf16 MFMA GEMM: C = A @ B^T + bias (validated rounds 2-20) ----------------
// Cb path: bf16 out, with QSCALE applied to cols < 1024 (q third; GEMM1 only).
// Cf path: f32 out (GEMM2).  XCD-swizzled lid (nwg % 8 == 0).
__global__ __launch_bounds__(256) void gemm_mfma_bt(
    const unsigned short* __restrict__ A,   // [M][K] bf16
    const unsigned short* __restrict__ B,   // [N][K] bf16
    const float* __restrict__ bias,         // [N] f32
    float* __restrict__ Cf,                 // f32 out (or null)
    unsigned short* __restrict__ Cb,        // bf16 out (or null)
    int M, int N, int K)
{
    __shared__ char As[128 * 128];
    __shared__ char Bs[128 * 128];

    const int tid  = threadIdx.x;
    const int lane = tid & 63;
    const int w    = tid >> 6;
    const int wm   = w >> 1;
    const int wn   = w & 1;

    const int gx  = gridDim.x;
    const int lid = blockIdx.y * gx + blockIdx.x;
    const int nwg = gx * gridDim.y;
    const int cpx = nwg >> 3;                 // nwg % 8 == 0 (768, 256)
    const int swz = (lid & 7) * cpx + (lid >> 3);
    const int m0 = (swz / gx) * 128;
    const int n0 = (swz % gx) * 128;

    f32x4 acc[4][4];
#pragma unroll
    for (int i = 0; i < 4; ++i)
#pragma unroll
        for (int j = 0; j < 4; ++j) acc[i][j] = (f32x4){0.f, 0.f, 0.f, 0.f};

    const int wbase = (tid & ~63);

    for (int k0 = 0; k0 < K; k0 += 64) {
        const char* Ag = (const char*)(A + (size_t)m0 * K + k0);
        const char* Bg = (const char*)(B + (size_t)n0 * K + k0);
#pragma unroll
        for (int i = 0; i < 4; ++i) {
            const int c = i * 256 + tid;
            const int row = c >> 3, cin = c & 7;
            const size_t goff = (size_t)row * (K * 2) + (size_t)((cin ^ (row & 7)) << 4);
            GLOAD_LDS16(Ag + goff, As + (i * 256 + wbase) * 16);
            GLOAD_LDS16(Bg + goff, Bs + (i * 256 + wbase) * 16);
        }
        __syncthreads();

#pragma unroll
        for (int ks = 0; ks < 2; ++ks) {
            const int kch = ks * 4 + (lane >> 4);
            bf16x8 a[4], b[4];
#pragma unroll
            for (int mi = 0; mi < 4; ++mi)
                a[mi] = frag_ld(As, wm * 64 + mi * 16 + (lane & 15), kch);
#pragma unroll
            for (int ni = 0; ni < 4; ++ni)
                b[ni] = frag_ld(Bs, wn * 64 + ni * 16 + (lane & 15), kch);
#pragma unroll
            for (int mi = 0; mi < 4; ++mi)
#pragma unroll
                for (int ni = 0; ni < 4; ++ni)
                    acc[mi][ni] = __builtin_amdgcn_mfma_f32_16x16x32_bf16(
                        a[mi], b[ni], acc[mi][ni], 0, 0, 0);
        }
        __syncthreads();
    }

    const int lc  = lane & 15;
    const int lr4 = (lane >> 4) * 4;
#pragma unroll
    for (int ni = 0; ni < 4; ++ni) {
        const int gcol = n0 + wn * 64 + ni * 16 + lc;
        const float bv = bias[gcol];
        const float scl = (Cb && gcol < GC) ? QSCALE : 1.f;   // q third pre-scale
#pragma unroll
        for (int mi = 0; mi < 4; ++mi) {
            const int grow0 = m0 + wm * 64 + mi * 16 + lr4;
#pragma unroll
            for (int j = 0; j < 4; ++j) {
                const float v = (acc[mi][ni][j] + bv) * scl;
                if (Cb) Cb[(size_t)(grow0 + j) * N + gcol] = f2bf(v);
                else    Cf[(size_t)(grow0 + j) * N + gcol] = v;
            }
        }
    }
}

// ---------------- V transpose + PV-slot permutation (validated r18) ----------------
// Vt[bh][d][32 tiles x 64 perm-slots]: position p = 32s + 8*l4 + e holds
// V[t = 32s + 16*(e>>2) + 4*l4 + (e&3)][d] — matches the P B-fragment slot map.
__global__ __launch_bounds__(256) void transpose_v(
    const unsigned short* __restrict__ qkvb, unsigned short* __restrict__ Vt)
{
    __shared__ unsigned short vt[64][72];
    const int tid = threadIdx.x;
    const int t0  = blockIdx.x * 64;
    const int bh  = blockIdx.y;
    const int b = bh >> 4, h = bh & 15;
    const unsigned short* src = qkvb + (size_t)(b * GT_SEQ) * (3 * GC) + 2 * GC + h * GDH;
    unsigned short* dstb = Vt + (size_t)bh * GDH * GT_SEQ;

#pragma unroll
    for (int i = 0; i < 2; ++i) {
        const int c = i * 256 + tid;
        const int tr = c >> 3, ch = c & 7;
        *reinterpret_cast<u16x8*>(&vt[tr][ch * 8]) =
            *reinterpret_cast<const u16x8*>(src + (size_t)(t0 + tr) * (3 * GC) + ch * 8);
    }
    __syncthreads();
#pragma unroll
    for (int i = 0; i < 2; ++i) {
        const int c = i * 256 + tid;
        const int d = c >> 3, ch = c & 7;
        const int s = ch >> 2, l4p = ch & 3;
        u16x8 o;
#pragma unroll
        for (int e = 0; e < 8; ++e) {
            const int tp = s * 32 + (e >> 2) * 16 + l4p * 4 + (e & 3);
            o[e] = vt[tp][d];
        }
        *reinterpret_cast<u16x8*>(dstb + (size_t)d * GT_SEQ + t0 + ch * 8) = o;
    }
}

// ---------------- flash attention v9f: r18 core, Q pre-scaled upstream, NO setprio ----------------
// (r20's setprio regressed: flash is barrier-synced lockstep -> m190 regime, not m191)
__global__ __launch_bounds__(256) void flash_attn_mfma9(
    const unsigned short* __restrict__ qkvb,  // [4096][3072] bf16: q(scaled)|k|v
    const unsigned short* __restrict__ Vt,    // [32][64][2048] (perm slots)
    unsigned short* __restrict__ O)           // [4096][1024] bf16
{
    __shared__ __align__(16) char Ks[2][64 * 128];   // K tile: row k, 64 d bf16, swizzled
    __shared__ __align__(16) char Vs[2][64 * 128];   // V^T tile: row d, 64 slots, swizzled

    const int tid  = threadIdx.x;
    const int lane = tid & 63;
    const int w    = tid >> 6;               // wave 0..3
    const int l15  = lane & 15;
    const int l4   = lane >> 4;
    const int bid  = blockIdx.x;              // 0..1023
    const int xcd  = bid & 7;
    const int rest = bid >> 3;                // 0..127
    const int bh   = xcd * 4 + (rest & 3);    // 0..31
    const int qb   = 31 - (rest >> 2);        // 0..31 (64-row blocks), heavy first
    const int b    = bh >> 4, h = bh & 15;
    const int q0w  = qb * 64 + w * 16;        // this wave's 16 q rows

    const unsigned short* hQ = qkvb + (size_t)(b * GT_SEQ) * (3 * GC) + h * GDH;
    const char* hKc = (const char*)(qkvb + (size_t)(b * GT_SEQ) * (3 * GC) + GC + h * GDH);
    const char* hVc = (const char*)(Vt + (size_t)bh * GDH * GT_SEQ);

    // all-ones A-fragment: acc_l = mfma(ones, P) -> l_q in every reg
    bf16x8 ones_a;
#pragma unroll
    for (int e = 0; e < 8; ++e) ones_a[e] = (short)0x3F80;

    // Q fragments (pre-scaled by GEMM1): qf[s], q row = l15, d = s*32+l4*8+e
    bf16x8 qf[2];
#pragma unroll
    for (int s = 0; s < 2; ++s)
        qf[s] = *reinterpret_cast<const bf16x8*>(
            hQ + (size_t)(q0w + l15) * (3 * GC) + s * 32 + l4 * 8);

    f32x4 acc_o[4];
    f32x4 acc_l = (f32x4){0.f, 0.f, 0.f, 0.f};
    float m_r = -1e30f;
#pragma unroll
    for (int nd = 0; nd < 4; ++nd) acc_o[nd] = (f32x4){0.f, 0.f, 0.f, 0.f};

    const int nt = qb + 1;
    const int wbase16 = (tid & ~63) * 16;

    // stage tile t into buffer bb: source pre-swizzled, dest linear (rule 21)
    auto STAGE = [&](int bb, int t) {
        const int k0 = t * 64;
#pragma unroll
        for (int i = 0; i < 2; ++i) {
            const int c = i * 256 + tid;
            const int row = c >> 3, cin = c & 7;
            GLOAD_LDS16(hKc + (size_t)(k0 + row) * (3 * GC * 2) + ((cin ^ (row & 7)) << 4),
                        Ks[bb] + i * 4096 + wbase16);
            GLOAD_LDS16(hVc + (size_t)row * 4096 + (size_t)k0 * 2 + ((cin ^ (row & 7)) << 4),
                        Vs[bb] + i * 4096 + wbase16);
        }
    };

    STAGE(0, 0);
    __syncthreads();

    for (int t = 0; t < nt; ++t) {
        if (t + 1 < nt) STAGE((t + 1) & 1, t + 1);

        const int k0 = t * 64;
        const char* Kb = Ks[t & 1];
        const char* Vb = Vs[t & 1];

        {
            // ---- QK^T swapped: S^T = mfma(K, Q), K fragments from LDS ----
            f32x4 s_acc[4];
#pragma unroll
            for (int ni = 0; ni < 4; ++ni) s_acc[ni] = (f32x4){0.f, 0.f, 0.f, 0.f};
#pragma unroll
            for (int s = 0; s < 2; ++s) {
                bf16x8 kf[4];
#pragma unroll
                for (int ni = 0; ni < 4; ++ni)
                    kf[ni] = frag_ld(Kb, ni * 16 + l15, s * 4 + l4);
#pragma unroll
                for (int ni = 0; ni < 4; ++ni)
                    s_acc[ni] = __builtin_amdgcn_mfma_f32_16x16x32_bf16(
                        kf[ni], qf[s], s_acc[ni], 0, 0, 0);
            }

            // ---- causal mask (partial tiles only): k > q -> -inf ----
            if (k0 + 63 > q0w) {
#pragma unroll
                for (int ni = 0; ni < 4; ++ni)
#pragma unroll
                    for (int j = 0; j < 4; ++j)
                        if (k0 + ni * 16 + l4 * 4 + j > q0w + l15)
                            s_acc[ni][j] = -1e30f;
            }

            // ---- deferred-max: in-lane partial max, rare rescale ----
            float r = fmaxf(fmaxf(s_acc[0][0], s_acc[0][1]),
                            fmaxf(s_acc[0][2], s_acc[0][3]));
#pragma unroll
            for (int ni = 1; ni < 4; ++ni)
                r = fmaxf(r, fmaxf(fmaxf(s_acc[ni][0], s_acc[ni][1]),
                                   fmaxf(s_acc[ni][2], s_acc[ni][3])));
            const int ok = (r <= m_r + 8.f) ? 1 : 0;
            if (!__all(ok)) {
                r = fmaxf(r, __shfl_xor(r, 16));
                r = fmaxf(r, __shfl_xor(r, 32));
                const float mnew = fmaxf(m_r, r);
                const float corr = hw_exp2(m_r - mnew);
                m_r = mnew;
                acc_l *= corr;
#pragma unroll
                for (int nd = 0; nd < 4; ++nd) acc_o[nd] *= corr;
            }

            // ---- exp2 + cvt_pk + PV per s; l via ones-MFMA; V via frag_ld ----
#pragma unroll
            for (int s = 0; s < 2; ++s) {
                union { u32 w4[4]; bf16x8 v; } pw;
                {
                    f32x4 pa, pb;
#pragma unroll
                    for (int j = 0; j < 4; ++j) {
                        pa[j] = hw_exp2(s_acc[2 * s + 0][j] - m_r);
                        pb[j] = hw_exp2(s_acc[2 * s + 1][j] - m_r);
                    }
                    pw.w4[0] = pk_bf16(pa[0], pa[1]);
                    pw.w4[1] = pk_bf16(pa[2], pa[3]);
                    pw.w4[2] = pk_bf16(pb[0], pb[1]);
                    pw.w4[3] = pk_bf16(pb[2], pb[3]);
                }
                acc_l = __builtin_amdgcn_mfma_f32_16x16x32_bf16(
                    ones_a, pw.v, acc_l, 0, 0, 0);
#pragma unroll
                for (int nd = 0; nd < 4; ++nd) {
                    const bf16x8 vf = frag_ld(Vb, nd * 16 + l15, s * 4 + l4);
                    acc_o[nd] = __builtin_amdgcn_mfma_f32_16x16x32_bf16(
                        vf, pw.v, acc_o[nd], 0, 0, 0);
                }
            }
        }

        __syncthreads();
    }

    // ---- epilogue: l = acc_l[0] (same in all regs), normalize, store ----
    {
        const float inv = 1.f / acc_l[0];
        const int q = q0w + l15;
        const size_t rbase = (size_t)(b * GT_SEQ + q) * GC + h * GDH;
#pragma unroll
        for (int nd = 0; nd < 4; ++nd) {
            ushort4 ov;
            ov.x = f2bf(acc_o[nd][0] * inv);
            ov.y = f2bf(acc_o[nd][1] * inv);
            ov.z = f2bf(acc_o[nd][2] * inv);
            ov.w = f2bf(acc_o[nd][3] * inv);
            *reinterpret_cast<ushort4*>(&O[rbase + nd * 16 + l4 * 4]) = ov;
        }
    }
}

extern "C" void kernel_launch(void* const* d_in, const int* in_sizes, int n_in,
                              void* d_out, int out_size, void* d_ws, size_t ws_size,
                              hipStream_t stream) {
    (void)in_sizes; (void)n_in; (void)out_size; (void)ws_size;
    const float* x      = (const float*)d_in[0];
    const float* w_attn = (const float*)d_in[1];
    const float* b_attn = (const float*)d_in[2];
    const float* w_proj = (const float*)d_in[3];
    const float* b_proj = (const float*)d_in[4];
    float* out = (float*)d_out;

    unsigned short* xb   = (unsigned short*)d_ws;            // [4096][1024]
    unsigned short* wab  = xb   + (size_t)GM * GC;           // [3072][1024]
    unsigned short* wpb  = wab  + (size_t)3 * GC * GC;       // [1024][1024]
    unsigned short* qkvb = wpb  + (size_t)GC * GC;           // [4096][3072]
    unsigned short* Vt   = qkvb + (size_t)GM * 3 * GC;       // [32][64][2048]
    unsigned short* aob  = xb;   // reuse: xb dead after GEMM1

    // 0) fused casts: x(4M) | w_attn(3M) | w_proj(1M) = 8M elems
    cast3_f32_bf16<<<dim3(8192), dim3(256), 0, stream>>>(
        x, xb, GM * GC, w_attn, wab, 3 * GC * GC, w_proj, wpb);

    // 1) qkv = x @ w_attn^T + b_attn (bf16, q third pre-scaled). grid 24x32=768
    gemm_mfma_bt<<<dim3(3 * GC / 128, GM / 128), dim3(256), 0, stream>>>(
        xb, wab, b_attn, nullptr, qkvb, GM, 3 * GC, GC);

    // 1.5) V transpose (+ PV-slot permutation) from qkvb -> Vt
    transpose_v<<<dim3(GT_SEQ / 64, GB * GH), dim3(256), 0, stream>>>(qkvb, Vt);

    // 2) flash attention v9f -> aob
    flash_attn_mfma9<<<dim3(1024), dim3(256), 0, stream>>>(qkvb, Vt, aob);

    // 3) out = aob @ w_proj^T + b_proj (f32), grid 8x32 = 256 (%8==0)
    gemm_mfma_bt<<<dim3(GC / 128, GM / 128), dim3(256), 0, stream>>>(
        aob, wpb, b_proj, out, nullptr, GM, GC, GC);
}